// Round 1
// baseline (43641.150 us; speedup 1.0000x reference)
//
#include <hip/hip_runtime.h>
#include <math.h>

// Problem constants (reference: B,T,D,H = 32,512,512,1024)
#define B_  32
#define T_  512
#define D_  512
#define H_  1024
#define FH  4096   // 4*H
#define GRID_NB 512

// ---------------------------------------------------------------------------
// Workspace layout (bytes):
//   wht  : [4096][1024] fp32 (transposed Wh)   = 16,777,216   @ ws+0
//   hb0  : [32][1024] fp32                     =    131,072   @ ws+16777216
//   hb1  : [32][1024] fp32                     =    131,072
//   cbuf : [32][1024] fp32                     =    131,072
//   bar  : grid-barrier counters               =      4,096   @ ws+17170432
//   xgc  : [Tc][B][4H] fp32 chunk buffer       = Tc*524288    @ ws+17174528
// ---------------------------------------------------------------------------

// ---- transpose Wh[1024][4096] -> WhT[4096][1024] --------------------------
__global__ void transpose_wh(const float* __restrict__ wh, float* __restrict__ wht) {
    __shared__ float tl[32][33];
    const int n0 = blockIdx.x * 32;   // gridDim.x = 128
    const int k0 = blockIdx.y * 32;   // gridDim.y = 32
    const int tx = threadIdx.x, ty = threadIdx.y;   // block (32,8)
#pragma unroll
    for (int j = 0; j < 4; ++j) {
        int r = ty + j * 8;
        tl[r][tx] = wh[(size_t)(k0 + r) * FH + n0 + tx];
    }
    __syncthreads();
#pragma unroll
    for (int j = 0; j < 4; ++j) {
        int r = ty + j * 8;
        wht[(size_t)(n0 + r) * H_ + k0 + tx] = tl[tx][r];
    }
}

// ---- fp32 GEMM + bias for a chunk of timesteps ----------------------------
__global__ __launch_bounds__(256) void gemm_bias_chunk(
    const float* __restrict__ A, const float* __restrict__ W,
    const float* __restrict__ bias, float* __restrict__ out, int K, int t0) {
    __shared__ float As[16 * 132];
    __shared__ float Bs[16 * 132];
    const int t  = threadIdx.x;
    const int tn = t & 15, tm = t >> 4;
    const int n0 = blockIdx.x * 128;   // 32 n-tiles
    const int m0 = blockIdx.y * 128;   // Tc/4 m-tiles

    float acc[8][8];
#pragma unroll
    for (int i = 0; i < 8; ++i)
#pragma unroll
        for (int j = 0; j < 8; ++j) acc[i][j] = 0.f;

    for (int k0 = 0; k0 < K; k0 += 16) {
#pragma unroll
        for (int i = 0; i < 2; ++i) {   // A tile 128x16, store transposed As[k][m]
            int fid = t + i * 256;
            int m = fid >> 2, cc = fid & 3;
            int r = m0 + m;
            int arow = (r & 31) * 512 + t0 + (r >> 5);
            float4 av = *(const float4*)(A + (size_t)arow * K + k0 + cc * 4);
            As[(cc * 4 + 0) * 132 + m] = av.x;
            As[(cc * 4 + 1) * 132 + m] = av.y;
            As[(cc * 4 + 2) * 132 + m] = av.z;
            As[(cc * 4 + 3) * 132 + m] = av.w;
        }
#pragma unroll
        for (int i = 0; i < 2; ++i) {   // B tile 16x128, Bs[k][n]
            int fid = t + i * 256;
            int kk = fid >> 5, c = fid & 31;
            *(float4*)(Bs + kk * 132 + c * 4) =
                *(const float4*)(W + (size_t)(k0 + kk) * FH + n0 + c * 4);
        }
        __syncthreads();
#pragma unroll
        for (int kk = 0; kk < 16; ++kk) {
            float4 a0 = *(const float4*)(As + kk * 132 + tm * 8);
            float4 a1 = *(const float4*)(As + kk * 132 + tm * 8 + 4);
            float4 b0 = *(const float4*)(Bs + kk * 132 + tn * 4);
            float4 b1 = *(const float4*)(Bs + kk * 132 + 64 + tn * 4);
            float am[8] = {a0.x, a0.y, a0.z, a0.w, a1.x, a1.y, a1.z, a1.w};
            float bn[8] = {b0.x, b0.y, b0.z, b0.w, b1.x, b1.y, b1.z, b1.w};
#pragma unroll
            for (int mm = 0; mm < 8; ++mm)
#pragma unroll
                for (int nn = 0; nn < 8; ++nn) acc[mm][nn] += am[mm] * bn[nn];
        }
        __syncthreads();
    }

    float4 bb0 = *(const float4*)(bias + n0 + tn * 4);
    float4 bb1 = *(const float4*)(bias + n0 + 64 + tn * 4);
#pragma unroll
    for (int mm = 0; mm < 8; ++mm) {
        size_t orow = (size_t)(m0 + tm * 8 + mm);
        float4 v0, v1;
        v0.x = acc[mm][0] + bb0.x; v0.y = acc[mm][1] + bb0.y;
        v0.z = acc[mm][2] + bb0.z; v0.w = acc[mm][3] + bb0.w;
        v1.x = acc[mm][4] + bb1.x; v1.y = acc[mm][5] + bb1.y;
        v1.z = acc[mm][6] + bb1.z; v1.w = acc[mm][7] + bb1.w;
        *(float4*)(out + orow * FH + n0 + tn * 4)      = v0;
        *(float4*)(out + orow * FH + n0 + 64 + tn * 4) = v1;
    }
}

// ---- 2-level grid barrier (cumulative counters; bar reset per launch call) -
// bar[0]=gen, bar[32]=L2 cnt, bar[64+32g]=L1 cnt (g = blockIdx&15, 32 blocks/grp)
__device__ __forceinline__ void grid_barrier(unsigned* bar, unsigned k) {
    __syncthreads();
    if (threadIdx.x == 0) {
        __threadfence();   // release: push h stores to device scope (wbL2)
        unsigned* gen = bar;
        unsigned* l2  = bar + 32;
        unsigned* l1  = bar + 64 + (blockIdx.x & 15u) * 32u;
        if (__hip_atomic_fetch_add(l1, 1u, __ATOMIC_ACQ_REL,
                                   __HIP_MEMORY_SCOPE_AGENT) == k * 32u + 31u) {
            if (__hip_atomic_fetch_add(l2, 1u, __ATOMIC_ACQ_REL,
                                       __HIP_MEMORY_SCOPE_AGENT) == k * 16u + 15u) {
                __hip_atomic_store(gen, k + 1u, __ATOMIC_RELEASE,
                                   __HIP_MEMORY_SCOPE_AGENT);
            }
        }
        while (__hip_atomic_load(gen, __ATOMIC_RELAXED,
                                 __HIP_MEMORY_SCOPE_AGENT) < k + 1u)
            __builtin_amdgcn_s_sleep(4);
        __threadfence();   // acquire: invalidate L1/L2 so fresh h is visible
    }
    __syncthreads();
}

// ---- async global->LDS, 16B per lane --------------------------------------
__device__ __forceinline__ void gld_lds16(const float* g, float* l) {
    __builtin_amdgcn_global_load_lds(
        (const __attribute__((address_space(1))) unsigned int*)g,
        (__attribute__((address_space(3))) unsigned int*)l, 16, 0, 0);
}

// ---- persistent LSTM over a chunk of timesteps ----------------------------
// 512 blocks x 256 threads, cooperative. Block owns 2 h-columns -> 8 WhT rows
// staged in LDS ONCE. Per step: double-buffered h chunk staging via
// global_load_lds, same compute/reduce mapping as the verified per-step kernel.
__global__ __launch_bounds__(256, 2) void lstm_seq(
    const float* __restrict__ wht,    // [4096][1024]
    const float* __restrict__ xgc,    // [Tc][B][4H] chunk
    float* __restrict__ hb0,          // [32][1024]
    float* __restrict__ hb1,          // [32][1024]
    float* __restrict__ cbuf,         // [32][1024]
    float* __restrict__ out,          // [B][T][H]
    unsigned* __restrict__ bar,
    int t0, int Tc, int gbase)
{
    __shared__ __align__(16) float smem[16928];   // 67.7 KB -> 2 blocks/CU
    float* whs = smem;                 // 8 rows * 257 float4 = 8224 floats (persistent)
    float* hsA = smem + 8224;          // 4096 floats: h chunk buf A
    float* hsB = smem + 12448;         // 4096 floats: h chunk buf B
    float* sc  = smem + 8224;          // overlay (8448 floats) after compute
    float* g4  = smem + 16672;         // 256 floats

    const int t   = threadIdx.x;
    const int hc0 = blockIdx.x * 2;

    // stage WhT rows for this block's 8 gate-columns ONCE
    float4* whs4 = (float4*)whs;
    {
        const float4* wht4 = (const float4*)wht;
#pragma unroll
        for (int i = 0; i < 8; ++i) {
            int fid = t + i * 256;
            int r = fid >> 8, cc = fid & 255;
            int grow = (r >> 1) * H_ + hc0 + (r & 1);   // r = gt*2 + hcl
            whs4[r * 257 + cc] = wht4[(size_t)grow * 256 + cc];
        }
    }

    // cell state lives in a register for the whole launch (threads t<64)
    float creg = 0.f;
    if (t < 64) creg = cbuf[(size_t)(t >> 1) * H_ + hc0 + (t & 1)];

    const int gcg = t & 1;
    const int sl  = (t >> 1) & 31;
    const int bg  = t >> 6;

    for (int tt = t0; tt < t0 + Tc; ++tt) {
        const float* hp = (tt & 1) ? hb1 : hb0;
        float* hn       = (tt & 1) ? hb0 : hb1;
        const float* xg_t = xgc + (size_t)(tt - t0) * (B_ * FH);

        // prefetch this thread's xg value early (consumed in the reduce)
        float xgv = xg_t[(size_t)((t >> 1) & 31) * FH + (t >> 6) * H_ + hc0 + (t & 1)];

        float acc[4][8];
#pragma unroll
        for (int i = 0; i < 4; ++i)
#pragma unroll
            for (int j = 0; j < 8; ++j) acc[i][j] = 0.f;

        // stage h[32][128] chunk ch into buf (LDS layout [b][32 float4], linear)
        auto stage = [&](float* buf, int ch) {
#pragma unroll
            for (int i = 0; i < 4; ++i) {
                int fid = t + i * 256;
                int b = fid >> 5, cc = fid & 31;
                gld_lds16(hp + (size_t)b * H_ + ch * 128 + cc * 4,
                          buf + 4 * ((t & ~63) + i * 256));
            }
        };

        stage(hsA, 0);
#pragma unroll
        for (int ch = 0; ch < 8; ++ch) {
            // drains vmcnt (chunk ch DMA complete) + orders prev compute
            // before this iteration's DMA issue into the other buffer
            __syncthreads();
            if (ch < 7) stage((ch & 1) ? hsA : hsB, ch + 1);
            const float4* hs4p = (const float4*)((ch & 1) ? hsB : hsA);
            float4 w0 = whs4[(gcg * 4 + 0) * 257 + ch * 32 + sl];
            float4 w1 = whs4[(gcg * 4 + 1) * 257 + ch * 32 + sl];
            float4 w2 = whs4[(gcg * 4 + 2) * 257 + ch * 32 + sl];
            float4 w3 = whs4[(gcg * 4 + 3) * 257 + ch * 32 + sl];
#pragma unroll
            for (int bi = 0; bi < 8; ++bi) {
                float4 hv = hs4p[(bg * 8 + bi) * 32 + sl];
                acc[0][bi] += w0.x * hv.x + w0.y * hv.y + w0.z * hv.z + w0.w * hv.w;
                acc[1][bi] += w1.x * hv.x + w1.y * hv.y + w1.z * hv.z + w1.w * hv.w;
                acc[2][bi] += w2.x * hv.x + w2.y * hv.y + w2.z * hv.z + w2.w * hv.w;
                acc[3][bi] += w3.x * hv.x + w3.y * hv.y + w3.z * hv.z + w3.w * hv.w;
            }
        }
        __syncthreads();   // all computes done; hs region becomes sc overlay

#pragma unroll
        for (int gi = 0; gi < 4; ++gi)
#pragma unroll
            for (int bi = 0; bi < 8; ++bi)
                sc[((gcg * 4 + gi) * 32 + bg * 8 + bi) * 33 + sl] = acc[gi][bi];
        __syncthreads();

        {   // reduce 32 partials per output, add xg, stash in g4[gt][b*2+hcl]
            int hcl = t & 1, b = (t >> 1) & 31, gt = t >> 6;
            int r = gt * 2 + hcl;
            float s = 0.f;
#pragma unroll
            for (int j = 0; j < 32; ++j) s += sc[(r * 32 + b) * 33 + j];
            g4[gt * 64 + (t & 63)] = s + xgv;
        }
        __syncthreads();

        if (t < 64) {   // 2 hcols x 32 batches
            int hcl = t & 1, b = t >> 1;
            int hc = hc0 + hcl;
            float vi = g4[t], vf = g4[64 + t], vg = g4[128 + t], vo = g4[192 + t];
            float si = 1.f / (1.f + __expf(-vi));
            float sf = 1.f / (1.f + __expf(-vf));
            float so = 1.f / (1.f + __expf(-vo));
            float tg = tanhf(vg);
            float cn = sf * creg + si * tg;
            creg = cn;
            float hv = so * tanhf(cn);
            hn[(size_t)b * H_ + hc] = hv;
            out[(size_t)b * (T_ * H_) + (size_t)tt * H_ + hc] = hv;
        }

        if (tt != t0 + Tc - 1)
            grid_barrier(bar, (unsigned)(gbase + (tt - t0)));
    }

    if (t < 64) cbuf[(size_t)(t >> 1) * H_ + hc0 + (t & 1)] = creg;
}

// ---------------------------------------------------------------------------
extern "C" void kernel_launch(void* const* d_in, const int* in_sizes, int n_in,
                              void* d_out, int out_size, void* d_ws, size_t ws_size,
                              hipStream_t stream) {
    (void)in_sizes; (void)n_in; (void)out_size;
    const float* x   = (const float*)d_in[0];
    const float* Wx0 = (const float*)d_in[1];
    const float* Wh0 = (const float*)d_in[2];
    const float* b0  = (const float*)d_in[3];
    const float* Wx1 = (const float*)d_in[4];
    const float* Wh1 = (const float*)d_in[5];
    const float* b1  = (const float*)d_in[6];
    float* out = (float*)d_out;

    char* ws = (char*)d_ws;
    float* wht  = (float*)(ws);                      // 16,777,216 B
    float* hb0  = (float*)(ws + 16777216ull);        //    131,072 B
    float* hb1  = hb0 + 32 * 1024;
    float* cbuf = hb1 + 32 * 1024;
    unsigned* bar = (unsigned*)(ws + 17170432ull);   //      4,096 B
    float* xgc  = (float*)(ws + 17174528ull);        // Tc * 524,288 B

    const size_t base = 17174528ull;
    int Tc;
    if      (ws_size >= base + 512ull * 524288ull) Tc = 512;
    else if (ws_size >= base +  64ull * 524288ull) Tc = 64;
    else if (ws_size >= base +  16ull * 524288ull) Tc = 16;
    else                                           Tc = 4;

    // reset barrier counters once per call (captured in the graph -> replay-safe)
    hipMemsetAsync(bar, 0, 4096, stream);
    int gb = 0;

    for (int layer = 0; layer < 2; ++layer) {
        const float* Aptr = layer ? out : x;
        const float* Wxp  = layer ? Wx1 : Wx0;
        const float* Whp  = layer ? Wh1 : Wh0;
        const float* bp   = layer ? b1  : b0;
        const int    K    = layer ? H_  : D_;

        transpose_wh<<<dim3(128, 32), dim3(32, 8), 0, stream>>>(Whp, wht);
        hipMemsetAsync(hb0, 0, 131072, stream);
        hipMemsetAsync(cbuf, 0, 131072, stream);

        for (int t0 = 0; t0 < T_; t0 += Tc) {
            gemm_bias_chunk<<<dim3(32, Tc / 4), 256, 0, stream>>>(
                Aptr, Wxp, bp, xgc, K, t0);

            const float* a0 = wht; const float* a1 = xgc;
            float* a2 = hb0; float* a3 = hb1; float* a4 = cbuf; float* a5 = out;
            unsigned* a6 = bar; int a7 = t0; int a8 = Tc; int a9 = gb;
            void* kargs[] = {&a0, &a1, &a2, &a3, &a4, &a5, &a6, &a7, &a8, &a9};
            hipLaunchCooperativeKernel(lstm_seq, dim3(GRID_NB), dim3(256),
                                       kargs, 0, stream);
            gb += Tc - 1;
        }
    }
}

// Round 2
// 12184.302 us; speedup vs baseline: 3.5818x; 3.5818x over previous
//
#include <hip/hip_runtime.h>
#include <math.h>

// Problem constants (reference: B,T,D,H = 32,512,512,1024)
#define B_  32
#define T_  512
#define D_  512
#define H_  1024
#define FH  4096   // 4*H
#define GRID_NB 256

// ---------------------------------------------------------------------------
// Workspace layout (bytes):
//   wht  : [4096][1024] fp32 (transposed Wh)   = 16,777,216   @ ws+0
//   hb0  : [32][1024] fp32                     =    131,072   @ ws+16777216
//   hb1  : [32][1024] fp32                     =    131,072
//   cbuf : [32][1024] fp32                     =    131,072
//   bar  : grid-barrier counters               =      4,096   @ ws+17170432
//   xgc  : [Tc][B][4H] fp32 chunk buffer       = Tc*524288    @ ws+17174528
// ---------------------------------------------------------------------------

// ---- transpose Wh[1024][4096] -> WhT[4096][1024] --------------------------
__global__ void transpose_wh(const float* __restrict__ wh, float* __restrict__ wht) {
    __shared__ float tl[32][33];
    const int n0 = blockIdx.x * 32;   // gridDim.x = 128
    const int k0 = blockIdx.y * 32;   // gridDim.y = 32
    const int tx = threadIdx.x, ty = threadIdx.y;   // block (32,8)
#pragma unroll
    for (int j = 0; j < 4; ++j) {
        int r = ty + j * 8;
        tl[r][tx] = wh[(size_t)(k0 + r) * FH + n0 + tx];
    }
    __syncthreads();
#pragma unroll
    for (int j = 0; j < 4; ++j) {
        int r = ty + j * 8;
        wht[(size_t)(n0 + r) * H_ + k0 + tx] = tl[tx][r];
    }
}

// ---- fp32 GEMM + bias for a chunk of timesteps ----------------------------
__global__ __launch_bounds__(256) void gemm_bias_chunk(
    const float* __restrict__ A, const float* __restrict__ W,
    const float* __restrict__ bias, float* __restrict__ out, int K, int t0) {
    __shared__ float As[16 * 132];
    __shared__ float Bs[16 * 132];
    const int t  = threadIdx.x;
    const int tn = t & 15, tm = t >> 4;
    const int n0 = blockIdx.x * 128;
    const int m0 = blockIdx.y * 128;

    float acc[8][8];
#pragma unroll
    for (int i = 0; i < 8; ++i)
#pragma unroll
        for (int j = 0; j < 8; ++j) acc[i][j] = 0.f;

    for (int k0 = 0; k0 < K; k0 += 16) {
#pragma unroll
        for (int i = 0; i < 2; ++i) {
            int fid = t + i * 256;
            int m = fid >> 2, cc = fid & 3;
            int r = m0 + m;
            int arow = (r & 31) * 512 + t0 + (r >> 5);
            float4 av = *(const float4*)(A + (size_t)arow * K + k0 + cc * 4);
            As[(cc * 4 + 0) * 132 + m] = av.x;
            As[(cc * 4 + 1) * 132 + m] = av.y;
            As[(cc * 4 + 2) * 132 + m] = av.z;
            As[(cc * 4 + 3) * 132 + m] = av.w;
        }
#pragma unroll
        for (int i = 0; i < 2; ++i) {
            int fid = t + i * 256;
            int kk = fid >> 5, c = fid & 31;
            *(float4*)(Bs + kk * 132 + c * 4) =
                *(const float4*)(W + (size_t)(k0 + kk) * FH + n0 + c * 4);
        }
        __syncthreads();
#pragma unroll
        for (int kk = 0; kk < 16; ++kk) {
            float4 a0 = *(const float4*)(As + kk * 132 + tm * 8);
            float4 a1 = *(const float4*)(As + kk * 132 + tm * 8 + 4);
            float4 b0 = *(const float4*)(Bs + kk * 132 + tn * 4);
            float4 b1 = *(const float4*)(Bs + kk * 132 + 64 + tn * 4);
            float am[8] = {a0.x, a0.y, a0.z, a0.w, a1.x, a1.y, a1.z, a1.w};
            float bn[8] = {b0.x, b0.y, b0.z, b0.w, b1.x, b1.y, b1.z, b1.w};
#pragma unroll
            for (int mm = 0; mm < 8; ++mm)
#pragma unroll
                for (int nn = 0; nn < 8; ++nn) acc[mm][nn] += am[mm] * bn[nn];
        }
        __syncthreads();
    }

    float4 bb0 = *(const float4*)(bias + n0 + tn * 4);
    float4 bb1 = *(const float4*)(bias + n0 + 64 + tn * 4);
#pragma unroll
    for (int mm = 0; mm < 8; ++mm) {
        size_t orow = (size_t)(m0 + tm * 8 + mm);
        float4 v0, v1;
        v0.x = acc[mm][0] + bb0.x; v0.y = acc[mm][1] + bb0.y;
        v0.z = acc[mm][2] + bb0.z; v0.w = acc[mm][3] + bb0.w;
        v1.x = acc[mm][4] + bb1.x; v1.y = acc[mm][5] + bb1.y;
        v1.z = acc[mm][6] + bb1.z; v1.w = acc[mm][7] + bb1.w;
        *(float4*)(out + orow * FH + n0 + tn * 4)      = v0;
        *(float4*)(out + orow * FH + n0 + 64 + tn * 4) = v1;
    }
}

// ---- coherent (MALL, L2-bypass) global access helpers ---------------------
__device__ __forceinline__ float4 ldg_cg4(const float* p) {
    float4 r;
    asm volatile("global_load_dwordx4 %0, %1, off sc0 sc1" : "=v"(r) : "v"(p));
    return r;
}
__device__ __forceinline__ float ldg_cg1(const float* p) {
    float r;
    asm volatile("global_load_dword %0, %1, off sc0 sc1" : "=v"(r) : "v"(p));
    return r;
}
__device__ __forceinline__ void stg_cg1(float* p, float v) {
    asm volatile("global_store_dword %0, %1, off sc0 sc1" :: "v"(p), "v"(v));
}
#define WAITVM(n) asm volatile("s_waitcnt vmcnt(" #n ")" ::: "memory")

// ---- fence-free 2-level grid barrier (relaxed atomics, cumulative) --------
// All shared data crossing the barrier is sc0sc1 (MALL-coherent), so no cache
// invalidates/writebacks are needed -- only vmcnt drain + counter handshake.
__device__ __forceinline__ void grid_barrier(unsigned* bar, unsigned k) {
    WAITVM(0);              // every wave: its h stores are ack'd at MALL
    __syncthreads();
    if (threadIdx.x == 0) {
        unsigned* gen = bar;
        unsigned* l2  = bar + 32;
        unsigned* l1  = bar + 64 + (blockIdx.x & 15u) * 32u;
        if (__hip_atomic_fetch_add(l1, 1u, __ATOMIC_RELAXED,
                                   __HIP_MEMORY_SCOPE_AGENT) == k * 16u + 15u) {
            if (__hip_atomic_fetch_add(l2, 1u, __ATOMIC_RELAXED,
                                       __HIP_MEMORY_SCOPE_AGENT) == k * 16u + 15u) {
                __hip_atomic_store(gen, k + 1u, __ATOMIC_RELAXED,
                                   __HIP_MEMORY_SCOPE_AGENT);
            }
        }
        while (__hip_atomic_load(gen, __ATOMIC_RELAXED,
                                 __HIP_MEMORY_SCOPE_AGENT) < k + 1u)
            __builtin_amdgcn_s_sleep(2);
    }
    __syncthreads();
}

// ---- persistent LSTM over a chunk of timesteps ----------------------------
// 256 blocks x 512 threads, cooperative. Block owns 4 h-columns (2 per
// 256-thread half). Wh rows live in REGISTERS (32 float4/thread, loaded once).
// h staged to LDS via a counted-vmcnt register pipeline of coherent loads.
__global__ __launch_bounds__(512, 2) void lstm_seq(
    const float* __restrict__ wht,    // [4096][1024]
    const float* __restrict__ xgc,    // [Tc][B][4H] chunk
    float* __restrict__ hb0,          // [32][1024]
    float* __restrict__ hb1,          // [32][1024]
    float* __restrict__ cbuf,         // [32][1024]
    float* __restrict__ out,          // [B][T][H]
    unsigned* __restrict__ bar,
    int t0, int Tc, int gbase)
{
    __shared__ __align__(16) float smem[17408];   // 69,632 B
    // hsA: smem[0..4095] (f4 x1024), hsB: smem[4096..8191]  (chunk dbuf)
    // sc overlay: half0 smem[0..8447], half1 smem[8448..16895]
    // g4: smem[16896 + q*256 ..]
    float4* hsA4 = (float4*)smem;
    float4* hsB4 = hsA4 + 1024;

    const int t   = threadIdx.x;
    const int q   = t >> 8;           // half (0/1): owns cols hc0+2q, hc0+2q+1
    const int u   = t & 255;
    const int hc0 = blockIdx.x * 4;

    const int gcg = u & 1;
    const int sl  = (u >> 1) & 31;
    const int bg  = u >> 6;           // 0..3 (batch group of 8)

    // ---- Wh rows -> registers, once (plain cached loads) ----
    const float4* wt4 = (const float4*)wht;
    int wr0, wr1, wr2, wr3;
    {
        int r0 = gcg * 4;
        wr0 = (((r0 + 0) >> 1) * H_ + hc0 + q * 2 + ((r0 + 0) & 1)) * 256;
        wr1 = (((r0 + 1) >> 1) * H_ + hc0 + q * 2 + ((r0 + 1) & 1)) * 256;
        wr2 = (((r0 + 2) >> 1) * H_ + hc0 + q * 2 + ((r0 + 2) & 1)) * 256;
        wr3 = (((r0 + 3) >> 1) * H_ + hc0 + q * 2 + ((r0 + 3) & 1)) * 256;
    }
#define DECLW(ch) \
    float4 w##ch##0 = wt4[wr0 + (ch) * 32 + sl]; \
    float4 w##ch##1 = wt4[wr1 + (ch) * 32 + sl]; \
    float4 w##ch##2 = wt4[wr2 + (ch) * 32 + sl]; \
    float4 w##ch##3 = wt4[wr3 + (ch) * 32 + sl];
    DECLW(0) DECLW(1) DECLW(2) DECLW(3) DECLW(4) DECLW(5) DECLW(6) DECLW(7)

    // cell state in register for the whole launch (threads u<64 of each half)
    float creg = 0.f;
    if (u < 64) creg = cbuf[(size_t)(u >> 1) * H_ + hc0 + q * 2 + (u & 1)];

    const int hoff0 = (t >> 5) * H_ + (t & 31) * 4;   // float offset, rows 0..15
    const int hoff1 = hoff0 + 16 * H_;                // rows 16..31
    float* scq = smem + q * 8448;
    float* g4q = smem + 16896 + q * 256;

    for (int tt = t0; tt < t0 + Tc; ++tt) {
        const float* hp = (tt & 1) ? hb1 : hb0;
        float* hn       = (tt & 1) ? hb0 : hb1;
        const float* xg_t = xgc + (size_t)(tt - t0) * (B_ * FH);

        // xg for this thread's reduce output (coherent load keeps the counted
        // vmcnt stream exact: it is the OLDEST op, retires first)
        float xgv = ldg_cg1(xg_t + (size_t)((u >> 1) & 31) * FH +
                            (u >> 6) * H_ + hc0 + q * 2 + (u & 1));

        float acc[4][8];
#pragma unroll
        for (int i = 0; i < 4; ++i)
#pragma unroll
            for (int j = 0; j < 8; ++j) acc[i][j] = 0.f;

        float4 ra0, ra1, ra2, ra3, ra4, ra5, ra6, ra7;
        float4 rb0, rb1, rb2, rb3, rb4, rb5, rb6, rb7;
#define ISSUE(ch) do { \
        ra##ch = ldg_cg4(hp + hoff0 + (ch) * 128); \
        rb##ch = ldg_cg4(hp + hoff1 + (ch) * 128); } while (0)
#define WRITEC(ch, base) do { \
        (base)[t]       = ra##ch; \
        (base)[t + 512] = rb##ch; } while (0)
#define FMA4(a, wv, hv) a += wv.x*hv.x + wv.y*hv.y + wv.z*hv.z + wv.w*hv.w
#define COMPUTE(ch, base) do { \
        const float4* hbp = (const float4*)(base); \
        _Pragma("unroll") \
        for (int bi = 0; bi < 8; ++bi) { \
            float4 hv = hbp[(bg * 8 + bi) * 32 + sl]; \
            FMA4(acc[0][bi], w##ch##0, hv); \
            FMA4(acc[1][bi], w##ch##1, hv); \
            FMA4(acc[2][bi], w##ch##2, hv); \
            FMA4(acc[3][bi], w##ch##3, hv); \
        } } while (0)

        // counted-vmcnt pipeline, lookahead 4, LDS chunk double-buffer
        ISSUE(0); ISSUE(1); ISSUE(2); ISSUE(3);
        WAITVM(6); WRITEC(0, hsA4);
        __syncthreads();
        ISSUE(4); WAITVM(6); WRITEC(1, hsB4); COMPUTE(0, hsA4); __syncthreads();
        ISSUE(5); WAITVM(6); WRITEC(2, hsA4); COMPUTE(1, hsB4); __syncthreads();
        ISSUE(6); WAITVM(6); WRITEC(3, hsB4); COMPUTE(2, hsA4); __syncthreads();
        ISSUE(7); WAITVM(6); WRITEC(4, hsA4); COMPUTE(3, hsB4); __syncthreads();
        WAITVM(4); WRITEC(5, hsB4); COMPUTE(4, hsA4); __syncthreads();
        WAITVM(2); WRITEC(6, hsA4); COMPUTE(5, hsB4); __syncthreads();
        WAITVM(0); WRITEC(7, hsB4); COMPUTE(6, hsA4); __syncthreads();
        COMPUTE(7, hsB4);
        __syncthreads();   // hs dead; sc overlay begins

        // per-slice partials -> sc (same layout/order as verified kernel)
#pragma unroll
        for (int gi = 0; gi < 4; ++gi)
#pragma unroll
            for (int bi = 0; bi < 8; ++bi)
                scq[((gcg * 4 + gi) * 32 + bg * 8 + bi) * 33 + sl] = acc[gi][bi];
        __syncthreads();

        {   // reduce 32 partials per output, add xg
            int hcl = u & 1, b = (u >> 1) & 31, gt = u >> 6;
            int r = gt * 2 + hcl;
            float s = 0.f;
#pragma unroll
            for (int j = 0; j < 32; ++j) s += scq[(r * 32 + b) * 33 + j];
            g4q[gt * 64 + (u & 63)] = s + xgv;
        }
        __syncthreads();

        if (u < 64) {   // 2 hcols x 32 batches per half
            int hcl = u & 1, b = u >> 1;
            int hc = hc0 + q * 2 + hcl;
            float vi = g4q[u], vf = g4q[64 + u], vg = g4q[128 + u], vo = g4q[192 + u];
            float si = 1.f / (1.f + __expf(-vi));
            float sf = 1.f / (1.f + __expf(-vf));
            float so = 1.f / (1.f + __expf(-vo));
            float tg = tanhf(vg);
            float cn = sf * creg + si * tg;
            creg = cn;
            float hv = so * tanhf(cn);
            stg_cg1(hn + (size_t)b * H_ + hc, hv);        // coherent: next step reads
            out[(size_t)b * (T_ * H_) + (size_t)tt * H_ + hc] = hv;  // plain
        }

        if (tt != t0 + Tc - 1)
            grid_barrier(bar, (unsigned)(gbase + (tt - t0)));
    }

    if (u < 64)
        cbuf[(size_t)(u >> 1) * H_ + hc0 + q * 2 + (u & 1)] = creg;
}

// ---------------------------------------------------------------------------
extern "C" void kernel_launch(void* const* d_in, const int* in_sizes, int n_in,
                              void* d_out, int out_size, void* d_ws, size_t ws_size,
                              hipStream_t stream) {
    (void)in_sizes; (void)n_in; (void)out_size;
    const float* x   = (const float*)d_in[0];
    const float* Wx0 = (const float*)d_in[1];
    const float* Wh0 = (const float*)d_in[2];
    const float* b0  = (const float*)d_in[3];
    const float* Wx1 = (const float*)d_in[4];
    const float* Wh1 = (const float*)d_in[5];
    const float* b1  = (const float*)d_in[6];
    float* out = (float*)d_out;

    char* ws = (char*)d_ws;
    float* wht  = (float*)(ws);                      // 16,777,216 B
    float* hb0  = (float*)(ws + 16777216ull);        //    131,072 B
    float* hb1  = hb0 + 32 * 1024;
    float* cbuf = hb1 + 32 * 1024;
    unsigned* bar = (unsigned*)(ws + 17170432ull);   //      4,096 B
    float* xgc  = (float*)(ws + 17174528ull);        // Tc * 524,288 B

    const size_t base = 17174528ull;
    int Tc;
    if      (ws_size >= base + 512ull * 524288ull) Tc = 512;
    else if (ws_size >= base +  64ull * 524288ull) Tc = 64;
    else if (ws_size >= base +  16ull * 524288ull) Tc = 16;
    else                                           Tc = 4;

    hipMemsetAsync(bar, 0, 4096, stream);   // graph-replay-safe counter reset
    int gb = 0;

    for (int layer = 0; layer < 2; ++layer) {
        const float* Aptr = layer ? out : x;
        const float* Wxp  = layer ? Wx1 : Wx0;
        const float* Whp  = layer ? Wh1 : Wh0;
        const float* bp   = layer ? b1  : b0;
        const int    K    = layer ? H_  : D_;

        transpose_wh<<<dim3(128, 32), dim3(32, 8), 0, stream>>>(Whp, wht);
        hipMemsetAsync(hb0, 0, 131072, stream);
        hipMemsetAsync(cbuf, 0, 131072, stream);

        for (int t0 = 0; t0 < T_; t0 += Tc) {
            gemm_bias_chunk<<<dim3(32, Tc / 4), 256, 0, stream>>>(
                Aptr, Wxp, bp, xgc, K, t0);

            const float* a0 = wht; const float* a1 = xgc;
            float* a2 = hb0; float* a3 = hb1; float* a4 = cbuf; float* a5 = out;
            unsigned* a6 = bar; int a7 = t0; int a8 = Tc; int a9 = gb;
            void* kargs[] = {&a0, &a1, &a2, &a3, &a4, &a5, &a6, &a7, &a8, &a9};
            hipLaunchCooperativeKernel(lstm_seq, dim3(GRID_NB), dim3(512),
                                       kargs, 0, stream);
            gb += Tc - 1;
        }
    }
}